// Round 8
// baseline (664.584 us; speedup 1.0000x reference)
//
#include <hip/hip_runtime.h>
#include <cstdint>

typedef __bf16 bf16;
typedef __bf16 bf16x8 __attribute__((ext_vector_type(8)));
typedef float  f32x4  __attribute__((ext_vector_type(4)));

#define BARRIER()    asm volatile("s_barrier" ::: "memory")
#define WAIT_LGKM0() asm volatile("s_waitcnt lgkmcnt(0)" ::: "memory")
#define WAIT_VM(n)   asm volatile("s_waitcnt vmcnt(" #n ")" ::: "memory")

// ---------------------------------------------------------------------------
// Fused prep kernel: hf-GEMM (320 blocks) | hg-GEMM (90) | W2 transpose (640).
// ---------------------------------------------------------------------------
__device__ void gemm_small_body(
    const float* __restrict__ A, const float* __restrict__ Bm,
    const float* __restrict__ bias, bf16* __restrict__ Cout,
    int M, int N, int K, int bx, int by)
{
    __shared__ float As[64][20];
    __shared__ float Bs[16][68];
    const int tid = threadIdx.x;
    const int m0 = bx * 64, n0 = by * 64;
    const int tx = tid & 15, ty = tid >> 4;
    const int arow = tid >> 2, ak = (tid & 3) << 2;
    const int bk = tid >> 4, bc = (tid & 15) << 2;
    const bool avalid = (m0 + arow) < M;
    float acc[4][4] = {};

    for (int k0 = 0; k0 < K; k0 += 16) {
        float4 av = make_float4(0.f, 0.f, 0.f, 0.f);
        if (avalid) av = *(const float4*)&A[(size_t)(m0 + arow) * K + k0 + ak];
        float4 bv = *(const float4*)&Bm[(size_t)(k0 + bk) * N + n0 + bc];
        __syncthreads();
        *(float4*)&As[arow][ak] = av;
        *(float4*)&Bs[bk][bc] = bv;
        __syncthreads();
#pragma unroll
        for (int k = 0; k < 16; ++k) {
            float a[4], b[4];
#pragma unroll
            for (int i = 0; i < 4; ++i) a[i] = As[ty * 4 + i][k];
#pragma unroll
            for (int j = 0; j < 4; ++j) b[j] = Bs[k][tx * 4 + j];
#pragma unroll
            for (int i = 0; i < 4; ++i)
#pragma unroll
                for (int j = 0; j < 4; ++j) acc[i][j] += a[i] * b[j];
        }
    }
#pragma unroll
    for (int i = 0; i < 4; ++i) {
        int row = m0 + ty * 4 + i;
        if (row >= M) continue;
#pragma unroll
        for (int j = 0; j < 4; ++j) {
            int col = n0 + tx * 4 + j;
            float v = acc[i][j] + (bias ? bias[col] : 0.f);
            Cout[(size_t)row * N + col] = (bf16)v;
        }
    }
}

__device__ void w2t_body(const float* __restrict__ W2, bf16* __restrict__ W2T,
                         int bx, int by)
{
    __shared__ float t[32][33];
    const int tx = threadIdx.x & 31, ty = threadIdx.x >> 5;  // 32 x 8
    const int n0 = bx * 32, k0 = by * 32;
#pragma unroll
    for (int i = 0; i < 4; ++i)
        t[ty + i * 8][tx] = W2[(size_t)(k0 + ty + i * 8) * 1024 + n0 + tx];
    __syncthreads();
#pragma unroll
    for (int i = 0; i < 4; ++i)
        W2T[(size_t)(n0 + ty + i * 8) * 640 + k0 + tx] = (bf16)t[tx][ty + i * 8];
}

__global__ __launch_bounds__(256) void prep(
    const float* __restrict__ f, const float* __restrict__ g,
    const float* __restrict__ W1, const float* __restrict__ b1,
    const float* __restrict__ W2,
    bf16* __restrict__ hf, bf16* __restrict__ hgb, bf16* __restrict__ W2T)
{
    const int bid = blockIdx.x;
    if (bid < 320) {
        gemm_small_body(f, W1, nullptr, hf, 2048, 640, 1024, bid % 32, bid / 32);
    } else if (bid < 410) {
        int b = bid - 320;
        gemm_small_body(g, W1 + 1024 * 640, b1, hgb, 520, 640, 320, b % 9, b / 9);
    } else {
        int b = bid - 410;
        w2t_body(W2, W2T, b % 32, b / 32);
    }
}

// ---------------------------------------------------------------------------
// Stage 2: fused joint GEMM — A generated DIRECTLY IN MFMA FRAGMENT REGISTERS
// (no A LDS round-trip). BM=128 BN=128 BK=64, 256 thr = 4 waves (2Mx2N),
// wave tile 64x64 (64 AGPR acc). LDS: only Bs[2][128x64] = 32 KB, XOR-swizzle.
// Each lane owns 4 A-fragment rows (mi*16+l15) at k-chunk lg*8; per kk it
// loads hf/hgb bf16x8 at those addresses, computes relu(hf+hg) in-register,
// and feeds MFMA. LDS traffic drops 960 -> 384 cyc per block-tile.
// vmem queue (in-order retire): [DMA(t) | S_kk0(t) | DMA(t+1)] -> the
// compiler's S-reg waits retire DMA(t) before the tile-top barrier; the only
// hard wait is t=0's vmcnt(12).
// ---------------------------------------------------------------------------
__global__ __launch_bounds__(256, 3) void joint_main(
    const bf16* __restrict__ hf, const bf16* __restrict__ hgb,
    const bf16* __restrict__ W2T, const float* __restrict__ b2,
    float* __restrict__ out)
{
    __shared__ bf16 Bs[2][128 * 64];     // 32 KB total
    const int tid = threadIdx.x;
    const int n0 = blockIdx.x * 128;
    const int m0 = blockIdx.y * 128;

    const int wid = tid >> 6, lane = tid & 63;
    const int wr = wid >> 1, wc = wid & 1;       // 2 (M) x 2 (N) waves
    const int lg = lane >> 4, l15 = lane & 15;

    // --- per-mi A-source pointers, fragment-layout direct ---
    const bf16* hfp[4];
    const bf16* hgp[4];
#pragma unroll
    for (int mi = 0; mi < 4; ++mi) {
        int row = m0 + wr * 64 + mi * 16 + l15;
        int bt = row / 65;
        int uu = row - bt * 65;
        int bb = bt >> 8;
        hfp[mi] = hf  + (size_t)bt * 640 + lg * 8;
        hgp[mi] = hgb + (size_t)(bb * 65 + uu) * 640 + lg * 8;
    }

    f32x4 acc[4][4] = {};
    bf16x8 Sf[4], Sg[4];            // single A-source reg set (WAR-recycled)
    bf16x8 afr[4], bfr[4];

    auto loadS = [&](int kabs) {    // kabs = tile_k0 + kk*32
#pragma unroll
        for (int mi = 0; mi < 4; ++mi) {
            Sf[mi] = *(const bf16x8*)(hfp[mi] + kabs);
            Sg[mi] = *(const bf16x8*)(hgp[mi] + kabs);
        }
    };
    auto genAfr = [&]() {
#pragma unroll
        for (int mi = 0; mi < 4; ++mi) {
            bf16x8 O;
#pragma unroll
            for (int j = 0; j < 8; ++j) {
                float s = (float)Sf[mi][j] + (float)Sg[mi][j];
                O[j] = (bf16)fmaxf(s, 0.f);
            }
            afr[mi] = O;
        }
    };
    auto stageB = [&](int buf, int k0) {
        const char* w2b = (const char*)W2T + (size_t)k0 * 2;
#pragma unroll
        for (int call = 0; call < 4; ++call) {
            int chunk = call * 256 + tid;          // 0..1023
            int brow = chunk >> 3, c = chunk & 7;
            const char* src = w2b + (size_t)(n0 + brow) * 1280
                                  + ((c ^ (brow & 7)) << 4);
            __builtin_amdgcn_global_load_lds(
                (const __attribute__((address_space(1))) uint32_t*)src,
                (__attribute__((address_space(3))) uint32_t*)&Bs[buf][chunk << 3],
                16, 0, 0);
        }
    };
    auto mfmaHalf = [&](int buf, int kk) {
        const int clog = (kk << 2) + lg;
#pragma unroll
        for (int ni = 0; ni < 4; ++ni) {
            int row = wc * 64 + ni * 16 + l15;
            bfr[ni] = *(const bf16x8*)&Bs[buf][row * 64 + ((clog ^ (row & 7)) << 3)];
        }
        __builtin_amdgcn_s_setprio(1);
#pragma unroll
        for (int mi = 0; mi < 4; ++mi)
#pragma unroll
            for (int ni = 0; ni < 4; ++ni)
                acc[mi][ni] = __builtin_amdgcn_mfma_f32_16x16x32_bf16(
                    afr[mi], bfr[ni], acc[mi][ni], 0, 0, 0);
        __builtin_amdgcn_s_setprio(0);
    };

    // ---- prologue: DMA(0) first (oldest in queue), then S(kk0, t0) ----
    stageB(0, 0);
    loadS(0);

#pragma unroll 1
    for (int t = 0; t < 10; ++t) {
        const int cur = t & 1;
        BARRIER();                               // Bs[cur^1] reads (t-1) done
        if (t < 9) {
            stageB(cur ^ 1, (t + 1) * 64);       // DMA(t+1) into back buffer
            WAIT_VM(12);                         // retires DMA(t) (t=0 case)
        } else {
            WAIT_VM(8);                          // leaves S_kk0(9) in flight
        }
        BARRIER();                               // all waves' DMA(t) complete
        // ---- kk0 ----
        genAfr();                                // consumes S_kk0 (vmcnt auto)
        loadS(t * 64 + 32);                      // issue S_kk1; flight = kk0 MFMA
        mfmaHalf(cur, 0);
        // ---- kk1 ----
        genAfr();                                // consumes S_kk1
        if (t < 9) loadS((t + 1) * 64);          // issue S_kk0(t+1)
        mfmaHalf(cur, 1);
    }

    // ---- epilogue: +b2, fp32 stores ----
    float bv[4];
#pragma unroll
    for (int ni = 0; ni < 4; ++ni) bv[ni] = b2[n0 + wc * 64 + ni * 16 + l15];
#pragma unroll
    for (int mi = 0; mi < 4; ++mi) {
#pragma unroll
        for (int ni = 0; ni < 4; ++ni) {
            int col = n0 + wc * 64 + ni * 16 + l15;
#pragma unroll
            for (int j = 0; j < 4; ++j) {
                int row = m0 + wr * 64 + mi * 16 + lg * 4 + j;
                out[(size_t)row * 1024 + col] = acc[mi][ni][j] + bv[ni];
            }
        }
    }
}

// ---------------------------------------------------------------------------
extern "C" void kernel_launch(void* const* d_in, const int* in_sizes, int n_in,
                              void* d_out, int out_size, void* d_ws, size_t ws_size,
                              hipStream_t stream)
{
    const float* f  = (const float*)d_in[0];   // (8,256,1024)
    const float* g  = (const float*)d_in[1];   // (8,65,320)
    const float* W1 = (const float*)d_in[2];   // (1344,640)
    const float* b1 = (const float*)d_in[3];   // (640)
    const float* W2 = (const float*)d_in[4];   // (640,1024)
    const float* b2 = (const float*)d_in[5];   // (1024)
    float* out = (float*)d_out;                // (8,256,65,1024)

    bf16* hf  = (bf16*)d_ws;                   // 2048*640
    bf16* hgb = hf + 2048 * 640;               // 520*640 (g@W1g + b1)
    bf16* W2T = hgb + 520 * 640;               // 1024*640

    prep<<<1050, 256, 0, stream>>>(f, g, W1, b1, W2, hf, hgb, W2T);
    joint_main<<<dim3(8, 1040), 256, 0, stream>>>(hf, hgb, W2T, b2, out);
}

// Round 10
// 358.787 us; speedup vs baseline: 1.8523x; 1.8523x over previous
//
#include <hip/hip_runtime.h>
#include <cstdint>

typedef __bf16 bf16;
typedef __bf16 bf16x8 __attribute__((ext_vector_type(8)));
typedef float  f32x4  __attribute__((ext_vector_type(4)));

#define BARRIER()    asm volatile("s_barrier" ::: "memory")
#define WAIT_LGKM0() asm volatile("s_waitcnt lgkmcnt(0)" ::: "memory")
#define WAIT_VM(n)   asm volatile("s_waitcnt vmcnt(" #n ")" ::: "memory")

// ---------------------------------------------------------------------------
// Fused prep kernel: hf-GEMM (320 blocks) | hg-GEMM (90) | W2 transpose (640).
// ---------------------------------------------------------------------------
__device__ void gemm_small_body(
    const float* __restrict__ A, const float* __restrict__ Bm,
    const float* __restrict__ bias, bf16* __restrict__ Cout,
    int M, int N, int K, int bx, int by)
{
    __shared__ float As[64][20];
    __shared__ float Bs[16][68];
    const int tid = threadIdx.x;
    const int m0 = bx * 64, n0 = by * 64;
    const int tx = tid & 15, ty = tid >> 4;
    const int arow = tid >> 2, ak = (tid & 3) << 2;
    const int bk = tid >> 4, bc = (tid & 15) << 2;
    const bool avalid = (m0 + arow) < M;
    float acc[4][4] = {};

    for (int k0 = 0; k0 < K; k0 += 16) {
        float4 av = make_float4(0.f, 0.f, 0.f, 0.f);
        if (avalid) av = *(const float4*)&A[(size_t)(m0 + arow) * K + k0 + ak];
        float4 bv = *(const float4*)&Bm[(size_t)(k0 + bk) * N + n0 + bc];
        __syncthreads();
        *(float4*)&As[arow][ak] = av;
        *(float4*)&Bs[bk][bc] = bv;
        __syncthreads();
#pragma unroll
        for (int k = 0; k < 16; ++k) {
            float a[4], b[4];
#pragma unroll
            for (int i = 0; i < 4; ++i) a[i] = As[ty * 4 + i][k];
#pragma unroll
            for (int j = 0; j < 4; ++j) b[j] = Bs[k][tx * 4 + j];
#pragma unroll
            for (int i = 0; i < 4; ++i)
#pragma unroll
                for (int j = 0; j < 4; ++j) acc[i][j] += a[i] * b[j];
        }
    }
#pragma unroll
    for (int i = 0; i < 4; ++i) {
        int row = m0 + ty * 4 + i;
        if (row >= M) continue;
#pragma unroll
        for (int j = 0; j < 4; ++j) {
            int col = n0 + tx * 4 + j;
            float v = acc[i][j] + (bias ? bias[col] : 0.f);
            Cout[(size_t)row * N + col] = (bf16)v;
        }
    }
}

__device__ void w2t_body(const float* __restrict__ W2, bf16* __restrict__ W2T,
                         int bx, int by)
{
    __shared__ float t[32][33];
    const int tx = threadIdx.x & 31, ty = threadIdx.x >> 5;  // 32 x 8
    const int n0 = bx * 32, k0 = by * 32;
#pragma unroll
    for (int i = 0; i < 4; ++i)
        t[ty + i * 8][tx] = W2[(size_t)(k0 + ty + i * 8) * 1024 + n0 + tx];
    __syncthreads();
#pragma unroll
    for (int i = 0; i < 4; ++i)
        W2T[(size_t)(n0 + ty + i * 8) * 640 + k0 + tx] = (bf16)t[tx][ty + i * 8];
}

__global__ __launch_bounds__(256) void prep(
    const float* __restrict__ f, const float* __restrict__ g,
    const float* __restrict__ W1, const float* __restrict__ b1,
    const float* __restrict__ W2,
    bf16* __restrict__ hf, bf16* __restrict__ hgb, bf16* __restrict__ W2T)
{
    const int bid = blockIdx.x;
    if (bid < 320) {
        gemm_small_body(f, W1, nullptr, hf, 2048, 640, 1024, bid % 32, bid / 32);
    } else if (bid < 410) {
        int b = bid - 320;
        gemm_small_body(g, W1 + 1024 * 640, b1, hgb, 520, 640, 320, b % 9, b / 9);
    } else {
        int b = bid - 410;
        w2t_body(W2, W2T, b % 32, b / 32);
    }
}

// ---------------------------------------------------------------------------
// Stage 2: fused joint GEMM — m201-style 4-phase schedule, 2 blocks/CU.
// BM=128 BN=256 BK=64, 256 thr = 4 waves (1x4), wave tile 128x64 (128 AGPR).
// LDS 80 KB: As[128x64] SINGLE + Bs[2][256x64] dbuf, XOR-swizzle 16B chunks.
// K-accumulation: P0/P2 accumulate into acc[0..3] (rows 0-63), P1/P3 into
// acc[4..7] (rows 64-127) — kk=0 and kk=1 sum into the SAME accumulators
// (fixed R9's out-of-bounds acc[mh*4] with mh=2,3).
// genA stagger keeps As single-buffered: kh1-threads (waves 2-3) write k1(t)
// at t.P0 (k1(t-1) last read at t-1.P3); kh0-threads (waves 0-1) write
// k0(t+1) at t.P3 (k0(t) last read at P1). DMA(t+1) at P0, loadA(t+1) at P1;
// only explicit vm-wait is WAIT_VM(8) at P3.
// ---------------------------------------------------------------------------
__global__ __launch_bounds__(256, 2) void joint_main(
    const bf16* __restrict__ hf, const bf16* __restrict__ hgb,
    const bf16* __restrict__ W2T, const float* __restrict__ b2,
    float* __restrict__ out)
{
    __shared__ bf16 As[128 * 64];        // 16 KB, single-buffered
    __shared__ bf16 Bs[2][256 * 64];     // 64 KB double-buffered
    const int tid = threadIdx.x;
    const int n0 = blockIdx.x * 256;
    const int m0 = blockIdx.y * 128;

    // --- A-generation mapping: thread -> (row r, k-half kh) ---
    const int r  = tid & 127;              // row 0..127
    const int kh = tid >> 7;               // 0: k 0-31 (waves 0-1), 1: k 32-63
    int aoff[4];
#pragma unroll
    for (int c = 0; c < 4; ++c) {
        int cc = kh * 4 + c;               // logical 16B-chunk within row
        aoff[c] = r * 64 + ((cc ^ (r & 7)) << 3);
    }
    const int m  = m0 + r;
    const int bt = m / 65;
    const int uu = m - bt * 65;
    const int bb = bt >> 8;
    const bf16* hfp = hf  + (size_t)bt * 640 + kh * 32;
    const bf16* hgp = hgb + (size_t)(bb * 65 + uu) * 640 + kh * 32;
    const bool genrole1 = (kh == 1);       // waves 2-3 write k1 at P0

    // --- wave mapping: 1 (M) x 4 (N) waves, wave tile 128x64 ---
    const int wid = tid >> 6, lane = tid & 63;
    const int wc = wid;
    const int lg = lane >> 4, l15 = lane & 15;

    f32x4 acc[8][4] = {};
    bf16x8 SF[4], SG[4];                   // A-source regs (single set)
    bf16x8 afr[4], bfr[4];

    auto loadA = [&](int k0) {
#pragma unroll
        for (int c = 0; c < 4; ++c) {
            SF[c] = *(const bf16x8*)(hfp + k0 + c * 8);
            SG[c] = *(const bf16x8*)(hgp + k0 + c * 8);
        }
    };
    auto genA = [&]() {                    // relu(hf+hg) -> As (own 4 chunks)
#pragma unroll
        for (int c = 0; c < 4; ++c) {
            bf16x8 O;
#pragma unroll
            for (int i = 0; i < 8; ++i) {
                float s = (float)SF[c][i] + (float)SG[c][i];
                O[i] = (bf16)fmaxf(s, 0.f);
            }
            *(bf16x8*)&As[aoff[c]] = O;
        }
    };
    auto stageB = [&](int buf, int k0) {   // 32 KB via 8 x gload_lds(16B)
        const char* w2b = (const char*)W2T + (size_t)k0 * 2;
#pragma unroll
        for (int call = 0; call < 8; ++call) {
            int chunk = call * 256 + tid;          // 0..2047
            int brow = chunk >> 3, c = chunk & 7;
            const char* src = w2b + (size_t)(n0 + brow) * 1280
                                  + ((c ^ (brow & 7)) << 4);
            __builtin_amdgcn_global_load_lds(
                (const __attribute__((address_space(1))) uint32_t*)src,
                (__attribute__((address_space(3))) uint32_t*)&Bs[buf][chunk << 3],
                16, 0, 0);
        }
    };
    auto LDB = [&](int buf, int kk) {
#pragma unroll
        for (int ni = 0; ni < 4; ++ni) {
            int row = wc * 64 + ni * 16 + l15;
            bfr[ni] = *(const bf16x8*)&Bs[buf][row * 64 + ((((kk << 2) + lg) ^ (row & 7)) << 3)];
        }
    };
    auto LDA = [&](int kk, int mh) {       // mh in {0,1}: rows 0-63 / 64-127
#pragma unroll
        for (int i = 0; i < 4; ++i) {
            int row = (mh * 4 + i) * 16 + l15;
            afr[i] = *(const bf16x8*)&As[row * 64 + ((((kk << 2) + lg) ^ (row & 7)) << 3)];
        }
    };
    auto MFMA16 = [&](int mh) {            // accumulate into acc[mh*4 .. mh*4+3]
        __builtin_amdgcn_s_setprio(1);
#pragma unroll
        for (int i = 0; i < 4; ++i)
#pragma unroll
            for (int ni = 0; ni < 4; ++ni)
                acc[mh * 4 + i][ni] = __builtin_amdgcn_mfma_f32_16x16x32_bf16(
                    afr[i], bfr[ni], acc[mh * 4 + i][ni], 0, 0, 0);
        __builtin_amdgcn_s_setprio(0);
    };

    // ---- prologue: DMA(0); loadA(0); genA(0) full; sync ----
    stageB(0, 0);
    loadA(0);
    genA();            // implicit vm-wait drains loadA(0) (and older DMA(0))
    WAIT_LGKM0();
    BARRIER();

#pragma unroll 1
    for (int t = 0; t < 10; ++t) {
        const int cur = t & 1, nxt = cur ^ 1;
        // ---- P0: [waves 2-3: genA k1(t)] | issue DMA(t+1) | reads kk0/mh0+B
        if (t > 0 && genrole1) genA();       // k1 region of tile t
        if (t < 9) stageB(nxt, (t + 1) * 64);
        LDB(cur, 0); LDA(0, 0);
        BARRIER(); WAIT_LGKM0();
        MFMA16(0);                            // kk0 -> acc[0..3]
        BARRIER();
        // ---- P1: issue loadA(t+1) | reads kk0/mh1 (bfr reused)
        if (t < 9) loadA((t + 1) * 64);
        LDA(0, 1);
        BARRIER(); WAIT_LGKM0();
        MFMA16(1);                            // kk0 -> acc[4..7]
        BARRIER();
        // ---- P2: reads kk1/mh0 + B(kk1)
        LDB(cur, 1); LDA(1, 0);
        BARRIER(); WAIT_LGKM0();
        MFMA16(0);                            // kk1 -> acc[0..3] (same accs!)
        BARRIER();
        // ---- P3: [waves 0-1: genA k0(t+1)] | reads kk1/mh1 | counted wait
        if (t < 9 && !genrole1) genA();      // k0 region of tile t+1
        LDA(1, 1);
        if (t < 9) WAIT_VM(8);               // DMA(t+1) retired; loadA flies
        BARRIER(); WAIT_LGKM0();
        MFMA16(1);                            // kk1 -> acc[4..7]
        BARRIER();
    }

    // ---- epilogue: +b2, fp32 stores ----
    float bv[4];
#pragma unroll
    for (int ni = 0; ni < 4; ++ni) bv[ni] = b2[n0 + wc * 64 + ni * 16 + l15];
#pragma unroll
    for (int mi = 0; mi < 8; ++mi) {
#pragma unroll
        for (int ni = 0; ni < 4; ++ni) {
            int col = n0 + wc * 64 + ni * 16 + l15;
#pragma unroll
            for (int j = 0; j < 4; ++j) {
                int row = m0 + mi * 16 + lg * 4 + j;
                out[(size_t)row * 1024 + col] = acc[mi][ni][j] + bv[ni];
            }
        }
    }
}

// ---------------------------------------------------------------------------
extern "C" void kernel_launch(void* const* d_in, const int* in_sizes, int n_in,
                              void* d_out, int out_size, void* d_ws, size_t ws_size,
                              hipStream_t stream)
{
    const float* f  = (const float*)d_in[0];   // (8,256,1024)
    const float* g  = (const float*)d_in[1];   // (8,65,320)
    const float* W1 = (const float*)d_in[2];   // (1344,640)
    const float* b1 = (const float*)d_in[3];   // (640)
    const float* W2 = (const float*)d_in[4];   // (640,1024)
    const float* b2 = (const float*)d_in[5];   // (1024)
    float* out = (float*)d_out;                // (8,256,65,1024)

    bf16* hf  = (bf16*)d_ws;                   // 2048*640
    bf16* hgb = hf + 2048 * 640;               // 520*640 (g@W1g + b1)
    bf16* W2T = hgb + 520 * 640;               // 1024*640

    prep<<<1050, 256, 0, stream>>>(f, g, W1, b1, W2, hf, hgb, W2T);
    joint_main<<<dim3(4, 1040), 256, 0, stream>>>(hf, hgb, W2T, b2, out);
}